// Round 1
// baseline (2303.604 us; speedup 1.0000x reference)
//
#include <hip/hip_runtime.h>
#include <math.h>

typedef __attribute__((ext_vector_type(8))) short short8;
typedef __attribute__((ext_vector_type(4))) float f32x4;

#define R_ROIS 512
#define CCH 512
#define HH 50
#define WW 50
#define PPOOL 7
#define KDIM (CCH * PPOOL * PPOOL) /* 25088 */
#define NH 4096

__device__ __forceinline__ short f2bf(float f) {
  unsigned u = __builtin_bit_cast(unsigned, f);
  u += 0x7FFFu + ((u >> 16) & 1u);
  return (short)(u >> 16);
}
__device__ __forceinline__ float bf2f(short s) {
  unsigned u = ((unsigned)(unsigned short)s) << 16;
  return __builtin_bit_cast(float, u);
}

// ---------------- RoI max pool -> bf16 activation matrix A[512][25088] ---------
__global__ __launch_bounds__(256) void roi_pool_kernel(
    const float* __restrict__ x, const float* __restrict__ rois,
    const int* __restrict__ ridx, short* __restrict__ A) {
  __shared__ int hs[PPOOL], he[PPOOL], wss[PPOOL], wee[PPOOL];
  __shared__ int sidx;
  const int r = blockIdx.x;
  if (threadIdx.x == 0) {
    // raw rois columns: (ymin, xmin, ymax, xmax); reference permutes to (x,y,x,y)
    float ymin = rois[r * 4 + 0], xmin = rois[r * 4 + 1];
    float ymax = rois[r * 4 + 2], xmax = rois[r * 4 + 3];
    float sw = rintf(xmin * 0.0625f);
    float sh = rintf(ymin * 0.0625f);
    float ew = rintf(xmax * 0.0625f);
    float eh = rintf(ymax * 0.0625f);
    float bw = fmaxf(ew - sw + 1.0f, 1.0f) * (1.0f / 7.0f);
    float bh = fmaxf(eh - sh + 1.0f, 1.0f) * (1.0f / 7.0f);
    for (int p = 0; p < PPOOL; ++p) {
      wss[p] = (int)fminf(fmaxf(floorf(p * bw) + sw, 0.0f), 50.0f);
      wee[p] = (int)fminf(fmaxf(ceilf((p + 1) * bw) + sw, 0.0f), 50.0f);
      hs[p]  = (int)fminf(fmaxf(floorf(p * bh) + sh, 0.0f), 50.0f);
      he[p]  = (int)fminf(fmaxf(ceilf((p + 1) * bh) + sh, 0.0f), 50.0f);
    }
    sidx = ridx[r];
  }
  __syncthreads();
  const float* xb = x + (size_t)sidx * CCH * HH * WW;
  for (int o = threadIdx.x; o < KDIM; o += 256) {
    int c = o / 49;
    int pq = o - c * 49;
    int ph = pq / 7, pw = pq - ph * 7;
    const float* xc = xb + (size_t)c * (HH * WW);
    int h0 = hs[ph], h1 = he[ph], w0 = wss[pw], w1 = wee[pw];
    float mv = -INFINITY;
    for (int h = h0; h < h1; ++h) {
      const float* xr = xc + h * WW;
      for (int w = w0; w < w1; ++w) mv = fmaxf(mv, xr[w]);
    }
    A[(size_t)r * KDIM + o] = f2bf((h1 > h0 && w1 > w0) ? mv : 0.0f);
  }
}

// ---------------- bf16 MFMA GEMM: C = act(A[M,K] * B_f32[K,N] + bias) ---------
// 128x128 tile, BK=32, 4 waves (2x2), 16x16x32 MFMA. B converted fp32->bf16
// during transposed LDS staging so both fragment reads are contiguous b128.
template <bool RELU, bool OUTBF16>
__global__ __launch_bounds__(256) void gemm_kernel(
    const short* __restrict__ A, const float* __restrict__ B,
    const float* __restrict__ bias, void* __restrict__ out,
    int M, int N, int K) {
  __shared__ __align__(16) short As[128 * 40];  // As[row][k], stride 40
  __shared__ __align__(16) short Bs[128 * 40];  // Bs[n][k],  stride 40 (transposed)
  const int t = threadIdx.x;
  const int n0 = blockIdx.x * 128;
  const int m0 = blockIdx.y * 128;
  const int lane = t & 63, wid = t >> 6;
  const int wm = wid >> 1, wn = wid & 1;
  const int lr = lane & 15, kc = lane >> 4;
  f32x4 acc[4][4] = {};

  for (int k0 = 0; k0 < K; k0 += 32) {
    // ---- stage A (bf16, linear rows) ----
    {
      int row = t >> 2, seg = t & 3;
      *(short8*)&As[row * 40 + seg * 8] =
          *(const short8*)(A + (size_t)(m0 + row) * K + k0 + seg * 8);
      *(short8*)&As[(row + 64) * 40 + seg * 8] =
          *(const short8*)(A + (size_t)(m0 + row + 64) * K + k0 + seg * 8);
    }
    // ---- stage B (fp32 -> bf16, transpose into Bs[n][k]) ----
    {
      int kt = t >> 4;
      int n8 = (t & 15) * 8;
      #pragma unroll
      for (int it = 0; it < 2; ++it, kt += 16) {
        const float* bp = B + (size_t)(k0 + kt) * N + n0 + n8;
        float4 v0 = *(const float4*)bp;
        float4 v1 = *(const float4*)(bp + 4);
        Bs[(n8 + 0) * 40 + kt] = f2bf(v0.x);
        Bs[(n8 + 1) * 40 + kt] = f2bf(v0.y);
        Bs[(n8 + 2) * 40 + kt] = f2bf(v0.z);
        Bs[(n8 + 3) * 40 + kt] = f2bf(v0.w);
        Bs[(n8 + 4) * 40 + kt] = f2bf(v1.x);
        Bs[(n8 + 5) * 40 + kt] = f2bf(v1.y);
        Bs[(n8 + 6) * 40 + kt] = f2bf(v1.z);
        Bs[(n8 + 7) * 40 + kt] = f2bf(v1.w);
      }
    }
    __syncthreads();
    short8 a[4], b[4];
    #pragma unroll
    for (int m = 0; m < 4; ++m)
      a[m] = *(const short8*)&As[(wm * 64 + m * 16 + lr) * 40 + kc * 8];
    #pragma unroll
    for (int n = 0; n < 4; ++n)
      b[n] = *(const short8*)&Bs[(wn * 64 + n * 16 + lr) * 40 + kc * 8];
    #pragma unroll
    for (int m = 0; m < 4; ++m)
      #pragma unroll
      for (int n = 0; n < 4; ++n)
        acc[m][n] = __builtin_amdgcn_mfma_f32_16x16x32_bf16(a[m], b[n], acc[m][n], 0, 0, 0);
    __syncthreads();
  }

  // ---- epilogue: bias + optional relu; C/D map: col=lane&15, row=kc*4+j ----
  #pragma unroll
  for (int m = 0; m < 4; ++m) {
    #pragma unroll
    for (int n = 0; n < 4; ++n) {
      int col = n0 + wn * 64 + n * 16 + lr;
      float bv = bias[col];
      #pragma unroll
      for (int j = 0; j < 4; ++j) {
        int row = m0 + wm * 64 + m * 16 + kc * 4 + j;
        float v = acc[m][n][j] + bv;
        if (RELU) v = fmaxf(v, 0.0f);
        if (OUTBF16)
          ((short*)out)[(size_t)row * N + col] = f2bf(v);
        else
          ((float*)out)[(size_t)row * N + col] = v;
      }
    }
  }
}

// ---------------- small heads: roi_cls_locs (84) + roi_scores (21) ------------
__global__ __launch_bounds__(128) void head_kernel(
    const short* __restrict__ fc7, const float* __restrict__ Wc,
    const float* __restrict__ bc, const float* __restrict__ Wsv,
    const float* __restrict__ bs, float* __restrict__ out) {
  __shared__ float rowv[NH];
  const int r = blockIdx.x, t = threadIdx.x;
  for (int k = t; k < NH; k += 128) rowv[k] = bf2f(fc7[(size_t)r * NH + k]);
  __syncthreads();
  if (t < 84) {
    float acc = bc[t];
    #pragma unroll 4
    for (int k = 0; k < NH; ++k) acc += rowv[k] * Wc[(size_t)k * 84 + t];
    out[(size_t)r * 84 + t] = acc;
  } else if (t < 105) {
    int n = t - 84;
    float acc = bs[n];
    #pragma unroll 4
    for (int k = 0; k < NH; ++k) acc += rowv[k] * Wsv[(size_t)k * 21 + n];
    out[(size_t)R_ROIS * 84 + (size_t)r * 21 + n] = acc;
  }
}

extern "C" void kernel_launch(void* const* d_in, const int* in_sizes, int n_in,
                              void* d_out, int out_size, void* d_ws, size_t ws_size,
                              hipStream_t stream) {
  const float* x    = (const float*)d_in[0];
  const float* rois = (const float*)d_in[1];
  const int*   ridx = (const int*)d_in[2];
  const float* W1   = (const float*)d_in[3];
  const float* b1   = (const float*)d_in[4];
  const float* W2   = (const float*)d_in[5];
  const float* b2   = (const float*)d_in[6];
  const float* Wc   = (const float*)d_in[7];
  const float* bc   = (const float*)d_in[8];
  const float* Wsv  = (const float*)d_in[9];
  const float* bs   = (const float*)d_in[10];

  short* A   = (short*)d_ws;                    // [512][25088] bf16  (~25.7 MB)
  short* fc6 = A + (size_t)R_ROIS * KDIM;       // [512][4096]  bf16  (4 MB)
  short* fc7 = fc6 + (size_t)R_ROIS * NH;       // [512][4096]  bf16  (4 MB)

  roi_pool_kernel<<<R_ROIS, 256, 0, stream>>>(x, rois, ridx, A);
  gemm_kernel<true, true><<<dim3(32, 4), 256, 0, stream>>>(A, W1, b1, fc6, 512, 4096, KDIM);
  gemm_kernel<true, true><<<dim3(32, 4), 256, 0, stream>>>(fc6, W2, b2, fc7, 512, 4096, NH);
  head_kernel<<<R_ROIS, 128, 0, stream>>>(fc7, Wc, bc, Wsv, bs, (float*)d_out);
}

// Round 2
// 827.841 us; speedup vs baseline: 2.7827x; 2.7827x over previous
//
#include <hip/hip_runtime.h>
#include <math.h>

typedef __attribute__((ext_vector_type(8))) short short8;
typedef __attribute__((ext_vector_type(4))) short s16x4;
typedef __attribute__((ext_vector_type(4))) float f32x4;

#define R_ROIS 512
#define CCH 512
#define HH 50
#define WW 50
#define PPOOL 7
#define KDIM (CCH * PPOOL * PPOOL) /* 25088 */
#define NH 4096

__device__ __forceinline__ short f2bf(float f) {
  unsigned u = __builtin_bit_cast(unsigned, f);
  u += 0x7FFFu + ((u >> 16) & 1u);
  return (short)(u >> 16);
}
__device__ __forceinline__ float bf2f(short s) {
  unsigned u = ((unsigned)(unsigned short)s) << 16;
  return __builtin_bit_cast(float, u);
}

// ---------------- RoI max pool -> bf16 activation matrix A[512][25088] ---------
__global__ __launch_bounds__(256) void roi_pool_kernel(
    const float* __restrict__ x, const float* __restrict__ rois,
    const int* __restrict__ ridx, short* __restrict__ A) {
  __shared__ int hs[PPOOL], he[PPOOL], wss[PPOOL], wee[PPOOL];
  __shared__ int sidx;
  const int r = blockIdx.x;
  if (threadIdx.x == 0) {
    // raw rois columns: (ymin, xmin, ymax, xmax); reference permutes to (x,y,x,y)
    float ymin = rois[r * 4 + 0], xmin = rois[r * 4 + 1];
    float ymax = rois[r * 4 + 2], xmax = rois[r * 4 + 3];
    float sw = rintf(xmin * 0.0625f);
    float sh = rintf(ymin * 0.0625f);
    float ew = rintf(xmax * 0.0625f);
    float eh = rintf(ymax * 0.0625f);
    float bw = fmaxf(ew - sw + 1.0f, 1.0f) * (1.0f / 7.0f);
    float bh = fmaxf(eh - sh + 1.0f, 1.0f) * (1.0f / 7.0f);
    for (int p = 0; p < PPOOL; ++p) {
      wss[p] = (int)fminf(fmaxf(floorf(p * bw) + sw, 0.0f), 50.0f);
      wee[p] = (int)fminf(fmaxf(ceilf((p + 1) * bw) + sw, 0.0f), 50.0f);
      hs[p]  = (int)fminf(fmaxf(floorf(p * bh) + sh, 0.0f), 50.0f);
      he[p]  = (int)fminf(fmaxf(ceilf((p + 1) * bh) + sh, 0.0f), 50.0f);
    }
    sidx = ridx[r];
  }
  __syncthreads();
  const float* xb = x + (size_t)sidx * CCH * HH * WW;
  for (int o = threadIdx.x; o < KDIM; o += 256) {
    int c = o / 49;
    int pq = o - c * 49;
    int ph = pq / 7, pw = pq - ph * 7;
    const float* xc = xb + (size_t)c * (HH * WW);
    int h0 = hs[ph], h1 = he[ph], w0 = wss[pw], w1 = wee[pw];
    float mv = -INFINITY;
    for (int h = h0; h < h1; ++h) {
      const float* xr = xc + h * WW;
      for (int w = w0; w < w1; ++w) mv = fmaxf(mv, xr[w]);
    }
    A[(size_t)r * KDIM + o] = f2bf((h1 > h0 && w1 > w0) ? mv : 0.0f);
  }
}

// ---------------- bf16 MFMA split-K GEMM: part[z] = A[M,K] * B_f32[K,N] -------
// BM=128, BN=64, BK=32, S via grid.z. 256 threads = 4 waves (2x2), wave tile
// 64x32. B staged via per-thread k-gather (coalesced across n) + one b128
// LDS write -> no scalar transposed writes, no bank-conflict storm.
__global__ __launch_bounds__(256) void gemm_splitk_kernel(
    const short* __restrict__ A, const float* __restrict__ B,
    float* __restrict__ part, int M, int N, int K, int Ks) {
  __shared__ __align__(16) short As[128 * 40];  // As[row][k], stride 40
  __shared__ __align__(16) short Bs[64 * 40];   // Bs[n][k],  stride 40
  const int t = threadIdx.x;
  const int n0 = blockIdx.x * 64;
  const int m0 = blockIdx.y * 128;
  const int kbeg = blockIdx.z * Ks;
  const int kend = kbeg + Ks;
  const int lane = t & 63, wid = t >> 6;
  const int wm = wid >> 1, wn = wid & 1;
  const int lr = lane & 15, kc = lane >> 4;
  const int ar = t >> 2, asg = t & 3;   // A staging: rows ar, ar+64; 16B seg asg
  const int bn = t & 63, bkh = t >> 6;  // B staging: col bn, 8-k group bkh

  f32x4 acc[4][2] = {};

  for (int k0 = kbeg; k0 < kend; k0 += 32) {
    // ---- stage A (bf16 rows, vectorized) ----
    *(short8*)&As[ar * 40 + asg * 8] =
        *(const short8*)(A + (size_t)(m0 + ar) * K + k0 + asg * 8);
    *(short8*)&As[(ar + 64) * 40 + asg * 8] =
        *(const short8*)(A + (size_t)(m0 + ar + 64) * K + k0 + asg * 8);
    // ---- stage B: gather 8 k for one n (coalesced across lanes), 1 b128 write
    {
      const float* bp = B + (size_t)(k0 + bkh * 8) * N + n0 + bn;
      short8 v;
      #pragma unroll
      for (int j = 0; j < 8; ++j) v[j] = f2bf(bp[(size_t)j * N]);
      *(short8*)&Bs[bn * 40 + bkh * 8] = v;
    }
    __syncthreads();
    short8 a[4], b[2];
    #pragma unroll
    for (int m = 0; m < 4; ++m)
      a[m] = *(const short8*)&As[(wm * 64 + m * 16 + lr) * 40 + kc * 8];
    #pragma unroll
    for (int n = 0; n < 2; ++n)
      b[n] = *(const short8*)&Bs[(wn * 32 + n * 16 + lr) * 40 + kc * 8];
    #pragma unroll
    for (int m = 0; m < 4; ++m)
      #pragma unroll
      for (int n = 0; n < 2; ++n)
        acc[m][n] = __builtin_amdgcn_mfma_f32_16x16x32_bf16(a[m], b[n], acc[m][n], 0, 0, 0);
    __syncthreads();
  }

  // ---- write fp32 partial (no bias yet); C/D map: col=lane&15, row=kc*4+j ----
  float* pz = part + (size_t)blockIdx.z * M * N;
  #pragma unroll
  for (int m = 0; m < 4; ++m) {
    #pragma unroll
    for (int n = 0; n < 2; ++n) {
      int col = n0 + wn * 32 + n * 16 + lr;
      #pragma unroll
      for (int j = 0; j < 4; ++j) {
        int row = m0 + wm * 64 + m * 16 + kc * 4 + j;
        pz[(size_t)row * N + col] = acc[m][n][j];
      }
    }
  }
}

// ---------------- reduce split-K partials + bias + relu -> bf16 ---------------
__global__ __launch_bounds__(256) void reduce_relu_kernel(
    const float* __restrict__ part, const float* __restrict__ bias,
    short* __restrict__ out, int MN, int N) {
  int i = (blockIdx.x * 256 + threadIdx.x) * 4;
  if (i >= MN) return;
  float4 p0 = *(const float4*)(part + i);
  float4 p1 = *(const float4*)(part + MN + i);
  const float4 b = *(const float4*)(bias + (i & (N - 1)));
  s16x4 o;
  o.x = f2bf(fmaxf(p0.x + p1.x + b.x, 0.0f));
  o.y = f2bf(fmaxf(p0.y + p1.y + b.y, 0.0f));
  o.z = f2bf(fmaxf(p0.z + p1.z + b.z, 0.0f));
  o.w = f2bf(fmaxf(p0.w + p1.w + b.w, 0.0f));
  *(s16x4*)(out + i) = o;
}

// ---------------- small heads: roi_cls_locs (84) + roi_scores (21) ------------
__global__ __launch_bounds__(256) void head_kernel(
    const short* __restrict__ fc7, const float* __restrict__ Wc,
    const float* __restrict__ bc, const float* __restrict__ Wsv,
    const float* __restrict__ bs, float* __restrict__ out) {
  __shared__ float rowv[NH];
  __shared__ float partial[112];
  const int r = blockIdx.x, t = threadIdx.x;
  for (int k8 = t; k8 < NH / 8; k8 += 256) {
    short8 v = *(const short8*)(fc7 + (size_t)r * NH + k8 * 8);
    #pragma unroll
    for (int j = 0; j < 8; ++j) rowv[k8 * 8 + j] = bf2f(v[j]);
  }
  __syncthreads();
  const int g = t >> 7, c = t & 127;  // two k-halves of 2048
  float acc = 0.0f;
  if (c < 84) {
    const float* wp = Wc + c + (size_t)g * 2048 * 84;
    #pragma unroll 8
    for (int k = 0; k < 2048; ++k) acc += rowv[g * 2048 + k] * wp[(size_t)k * 84];
  } else if (c < 105) {
    const float* wp = Wsv + (c - 84) + (size_t)g * 2048 * 21;
    #pragma unroll 8
    for (int k = 0; k < 2048; ++k) acc += rowv[g * 2048 + k] * wp[(size_t)k * 21];
  }
  if (g == 0 && c < 105) partial[c] = acc;
  __syncthreads();
  if (g == 1 && c < 105) {
    float v = partial[c] + acc;
    if (c < 84)
      out[(size_t)r * 84 + c] = v + bc[c];
    else
      out[(size_t)R_ROIS * 84 + (size_t)r * 21 + (c - 84)] = v + bs[c - 84];
  }
}

extern "C" void kernel_launch(void* const* d_in, const int* in_sizes, int n_in,
                              void* d_out, int out_size, void* d_ws, size_t ws_size,
                              hipStream_t stream) {
  const float* x    = (const float*)d_in[0];
  const float* rois = (const float*)d_in[1];
  const int*   ridx = (const int*)d_in[2];
  const float* W1   = (const float*)d_in[3];
  const float* b1   = (const float*)d_in[4];
  const float* W2   = (const float*)d_in[5];
  const float* b2   = (const float*)d_in[6];
  const float* Wc   = (const float*)d_in[7];
  const float* bc   = (const float*)d_in[8];
  const float* Wsv  = (const float*)d_in[9];
  const float* bs   = (const float*)d_in[10];

  short* A    = (short*)d_ws;                   // [512][25088] bf16 (~25.7 MB)
  short* fc6  = A + (size_t)R_ROIS * KDIM;      // [512][4096]  bf16 (4 MB)
  short* fc7  = fc6 + (size_t)R_ROIS * NH;      // [512][4096]  bf16 (4 MB)
  float* part = (float*)(fc7 + (size_t)R_ROIS * NH);  // 2x[512][4096] f32 (16.8 MB)

  const int MN = R_ROIS * NH;

  roi_pool_kernel<<<R_ROIS, 256, 0, stream>>>(x, rois, ridx, A);

  // fc6: [512,25088] @ [25088,4096], split-K=2 (Ks=12544)
  gemm_splitk_kernel<<<dim3(NH / 64, R_ROIS / 128, 2), 256, 0, stream>>>(
      A, W1, part, R_ROIS, NH, KDIM, KDIM / 2);
  reduce_relu_kernel<<<MN / 4 / 256, 256, 0, stream>>>(part, b1, fc6, MN, NH);

  // fc7: [512,4096] @ [4096,4096], split-K=2 (Ks=2048)
  gemm_splitk_kernel<<<dim3(NH / 64, R_ROIS / 128, 2), 256, 0, stream>>>(
      fc6, W2, part, R_ROIS, NH, NH, NH / 2);
  reduce_relu_kernel<<<MN / 4 / 256, 256, 0, stream>>>(part, b2, fc7, MN, NH);

  head_kernel<<<R_ROIS, 256, 0, stream>>>(fc7, Wc, bc, Wsv, bs, (float*)d_out);
}

// Round 3
// 716.251 us; speedup vs baseline: 3.2162x; 1.1558x over previous
//
#include <hip/hip_runtime.h>
#include <math.h>

typedef __attribute__((ext_vector_type(8))) short short8;
typedef __attribute__((ext_vector_type(4))) short s16x4;
typedef __attribute__((ext_vector_type(4))) float f32x4;

#define R_ROIS 512
#define CCH 512
#define HH 50
#define WW 50
#define PPOOL 7
#define KDIM (CCH * PPOOL * PPOOL) /* 25088 */
#define NH 4096

__device__ __forceinline__ short f2bf(float f) {
  unsigned u = __builtin_bit_cast(unsigned, f);
  u += 0x7FFFu + ((u >> 16) & 1u);
  return (short)(u >> 16);
}
__device__ __forceinline__ float bf2f(short s) {
  unsigned u = ((unsigned)(unsigned short)s) << 16;
  return __builtin_bit_cast(float, u);
}

// ---------------- RoI max pool -> bf16 activation matrix A[512][25088] ---------
__global__ __launch_bounds__(256) void roi_pool_kernel(
    const float* __restrict__ x, const float* __restrict__ rois,
    const int* __restrict__ ridx, short* __restrict__ A) {
  __shared__ int hs[PPOOL], he[PPOOL], wss[PPOOL], wee[PPOOL];
  __shared__ int sidx;
  const int r = blockIdx.x;
  if (threadIdx.x == 0) {
    // raw rois columns: (ymin, xmin, ymax, xmax); reference permutes to (x,y,x,y)
    float ymin = rois[r * 4 + 0], xmin = rois[r * 4 + 1];
    float ymax = rois[r * 4 + 2], xmax = rois[r * 4 + 3];
    float sw = rintf(xmin * 0.0625f);
    float sh = rintf(ymin * 0.0625f);
    float ew = rintf(xmax * 0.0625f);
    float eh = rintf(ymax * 0.0625f);
    float bw = fmaxf(ew - sw + 1.0f, 1.0f) * (1.0f / 7.0f);
    float bh = fmaxf(eh - sh + 1.0f, 1.0f) * (1.0f / 7.0f);
    for (int p = 0; p < PPOOL; ++p) {
      wss[p] = (int)fminf(fmaxf(floorf(p * bw) + sw, 0.0f), 50.0f);
      wee[p] = (int)fminf(fmaxf(ceilf((p + 1) * bw) + sw, 0.0f), 50.0f);
      hs[p]  = (int)fminf(fmaxf(floorf(p * bh) + sh, 0.0f), 50.0f);
      he[p]  = (int)fminf(fmaxf(ceilf((p + 1) * bh) + sh, 0.0f), 50.0f);
    }
    sidx = ridx[r];
  }
  __syncthreads();
  const float* xb = x + (size_t)sidx * CCH * HH * WW;
  for (int o = threadIdx.x; o < KDIM; o += 256) {
    int c = o / 49;
    int pq = o - c * 49;
    int ph = pq / 7, pw = pq - ph * 7;
    const float* xc = xb + (size_t)c * (HH * WW);
    int h0 = hs[ph], h1 = he[ph], w0 = wss[pw], w1 = wee[pw];
    float mv = -INFINITY;
    for (int h = h0; h < h1; ++h) {
      const float* xr = xc + h * WW;
      for (int w = w0; w < w1; ++w) mv = fmaxf(mv, xr[w]);
    }
    A[(size_t)r * KDIM + o] = f2bf((h1 > h0 && w1 > w0) ? mv : 0.0f);
  }
}

// ---------------- bf16 MFMA split-K GEMM, double-buffered pipeline ------------
// BM=128, BN=64, BK=32. Virtual grid (m=4, n=64, z=Z) swizzled so the 4
// m-siblings (sharing a B panel) are co-XCD. Per iteration: issue next-tile
// global loads (regs) -> ds_read+MFMA current buffer -> convert+ds_write other
// buffer -> one barrier. Load latency hides under compute (T14).
__global__ __launch_bounds__(256, 4) void gemm_splitk_kernel(
    const short* __restrict__ A, const float* __restrict__ B,
    float* __restrict__ part, int M, int N, int K, int Ks, int nblk) {
  __shared__ __align__(16) short As[2][128 * 40];  // [row][k], stride 40
  __shared__ __align__(16) short Bs[2][64 * 40];   // [n][k],  stride 40
  // XCD swizzle: vid = (bid%8)*nchunk + bid/8 keeps m-siblings co-XCD
  const int bid = blockIdx.x;
  const int vid = (bid & 7) * (nblk >> 3) + (bid >> 3);
  const int mb = vid & 3;
  const int nb = (vid >> 2) & 63;
  const int zb = vid >> 8;
  const int n0 = nb * 64;
  const int m0 = mb * 128;
  const int kbeg = zb * Ks;
  const int kend = kbeg + Ks;
  const int t = threadIdx.x;
  const int lane = t & 63, wid = t >> 6;
  const int wm = wid >> 1, wn = wid & 1;
  const int lr = lane & 15, kc = lane >> 4;
  const int ar = t >> 2, asg = t & 3;   // A staging: rows ar, ar+64; 16B seg asg
  const int bn = t & 63, bkh = t >> 6;  // B staging: col bn, 8-k group bkh

  const short* aptr0 = A + (size_t)(m0 + ar) * K + asg * 8;
  const short* aptr1 = A + (size_t)(m0 + ar + 64) * K + asg * 8;
  const float* bptr = B + (size_t)bkh * 8 * N + n0 + bn;

  f32x4 acc[4][2] = {};
  short8 a_r0, a_r1;
  float b_r[8];

  // prologue: stage tile kbeg into buffer 0
  a_r0 = *(const short8*)(aptr0 + kbeg);
  a_r1 = *(const short8*)(aptr1 + kbeg);
  #pragma unroll
  for (int j = 0; j < 8; ++j) b_r[j] = bptr[(size_t)(kbeg + j) * N];
  *(short8*)&As[0][ar * 40 + asg * 8] = a_r0;
  *(short8*)&As[0][(ar + 64) * 40 + asg * 8] = a_r1;
  {
    short8 v;
    #pragma unroll
    for (int j = 0; j < 8; ++j) v[j] = f2bf(b_r[j]);
    *(short8*)&Bs[0][bn * 40 + bkh * 8] = v;
  }
  __syncthreads();

  int cur = 0;
  for (int k0 = kbeg + 32; k0 <= kend; k0 += 32) {
    bool more = (k0 < kend);
    if (more) {  // 1) issue next-tile loads into regs
      a_r0 = *(const short8*)(aptr0 + k0);
      a_r1 = *(const short8*)(aptr1 + k0);
      #pragma unroll
      for (int j = 0; j < 8; ++j) b_r[j] = bptr[(size_t)(k0 + j) * N];
    }
    // 2) compute on current buffer (independent of the loads above)
    {
      short8 a[4], b[2];
      #pragma unroll
      for (int m = 0; m < 4; ++m)
        a[m] = *(const short8*)&As[cur][(wm * 64 + m * 16 + lr) * 40 + kc * 8];
      #pragma unroll
      for (int n = 0; n < 2; ++n)
        b[n] = *(const short8*)&Bs[cur][(wn * 32 + n * 16 + lr) * 40 + kc * 8];
      #pragma unroll
      for (int m = 0; m < 4; ++m)
        #pragma unroll
        for (int n = 0; n < 2; ++n)
          acc[m][n] = __builtin_amdgcn_mfma_f32_16x16x32_bf16(a[m], b[n], acc[m][n], 0, 0, 0);
    }
    if (more) {  // 3) wait loads (compiler vmcnt), convert, write other buffer
      *(short8*)&As[cur ^ 1][ar * 40 + asg * 8] = a_r0;
      *(short8*)&As[cur ^ 1][(ar + 64) * 40 + asg * 8] = a_r1;
      short8 v;
      #pragma unroll
      for (int j = 0; j < 8; ++j) v[j] = f2bf(b_r[j]);
      *(short8*)&Bs[cur ^ 1][bn * 40 + bkh * 8] = v;
      __syncthreads();
      cur ^= 1;
    }
  }

  // ---- write fp32 partial; C/D map: col=lane&15, row=kc*4+j ----
  float* pz = part + (size_t)zb * M * N;
  #pragma unroll
  for (int m = 0; m < 4; ++m) {
    #pragma unroll
    for (int n = 0; n < 2; ++n) {
      int col = n0 + wn * 32 + n * 16 + lr;
      #pragma unroll
      for (int j = 0; j < 4; ++j) {
        int row = m0 + wm * 64 + m * 16 + kc * 4 + j;
        pz[(size_t)row * N + col] = acc[m][n][j];
      }
    }
  }
}

// ---------------- reduce split-K partials + bias + relu -> bf16 ---------------
__global__ __launch_bounds__(256) void reduce_relu_kernel(
    const float* __restrict__ part, const float* __restrict__ bias,
    short* __restrict__ out, int MN, int N, int Z) {
  int i = (blockIdx.x * 256 + threadIdx.x) * 4;
  if (i >= MN) return;
  const float4 b = *(const float4*)(bias + (i & (N - 1)));
  float4 s = *(const float4*)(part + i);
  for (int z = 1; z < Z; ++z) {
    float4 p = *(const float4*)(part + (size_t)z * MN + i);
    s.x += p.x; s.y += p.y; s.z += p.z; s.w += p.w;
  }
  s16x4 o;
  o.x = f2bf(fmaxf(s.x + b.x, 0.0f));
  o.y = f2bf(fmaxf(s.y + b.y, 0.0f));
  o.z = f2bf(fmaxf(s.z + b.z, 0.0f));
  o.w = f2bf(fmaxf(s.w + b.w, 0.0f));
  *(s16x4*)(out + i) = o;
}

// ---------------- small heads: roi_cls_locs (84) + roi_scores (21) ------------
__global__ __launch_bounds__(256) void head_kernel(
    const short* __restrict__ fc7, const float* __restrict__ Wc,
    const float* __restrict__ bc, const float* __restrict__ Wsv,
    const float* __restrict__ bs, float* __restrict__ out) {
  __shared__ float rowv[NH];
  __shared__ float partial[112];
  const int r = blockIdx.x, t = threadIdx.x;
  for (int k8 = t; k8 < NH / 8; k8 += 256) {
    short8 v = *(const short8*)(fc7 + (size_t)r * NH + k8 * 8);
    #pragma unroll
    for (int j = 0; j < 8; ++j) rowv[k8 * 8 + j] = bf2f(v[j]);
  }
  __syncthreads();
  const int g = t >> 7, c = t & 127;  // two k-halves of 2048
  float acc = 0.0f;
  if (c < 84) {
    const float* wp = Wc + c + (size_t)g * 2048 * 84;
    #pragma unroll 8
    for (int k = 0; k < 2048; ++k) acc += rowv[g * 2048 + k] * wp[(size_t)k * 84];
  } else if (c < 105) {
    const float* wp = Wsv + (c - 84) + (size_t)g * 2048 * 21;
    #pragma unroll 8
    for (int k = 0; k < 2048; ++k) acc += rowv[g * 2048 + k] * wp[(size_t)k * 21];
  }
  if (g == 0 && c < 105) partial[c] = acc;
  __syncthreads();
  if (g == 1 && c < 105) {
    float v = partial[c] + acc;
    if (c < 84)
      out[(size_t)r * 84 + c] = v + bc[c];
    else
      out[(size_t)R_ROIS * 84 + (size_t)r * 21 + (c - 84)] = v + bs[c - 84];
  }
}

extern "C" void kernel_launch(void* const* d_in, const int* in_sizes, int n_in,
                              void* d_out, int out_size, void* d_ws, size_t ws_size,
                              hipStream_t stream) {
  const float* x    = (const float*)d_in[0];
  const float* rois = (const float*)d_in[1];
  const int*   ridx = (const int*)d_in[2];
  const float* W1   = (const float*)d_in[3];
  const float* b1   = (const float*)d_in[4];
  const float* W2   = (const float*)d_in[5];
  const float* b2   = (const float*)d_in[6];
  const float* Wc   = (const float*)d_in[7];
  const float* bc   = (const float*)d_in[8];
  const float* Wsv  = (const float*)d_in[9];
  const float* bs   = (const float*)d_in[10];

  short* A    = (short*)d_ws;                   // [512][25088] bf16 (~25.7 MB)
  short* fc6  = A + (size_t)R_ROIS * KDIM;      // [512][4096]  bf16 (4 MB)
  short* fc7  = fc6 + (size_t)R_ROIS * NH;      // [512][4096]  bf16 (4 MB)
  float* part = (float*)(fc7 + (size_t)R_ROIS * NH);  // Z x [512][4096] f32

  const int MN = R_ROIS * NH;
  const size_t base = ((size_t)R_ROIS * KDIM + 2 * (size_t)MN) * 2;
  int Z = (int)((ws_size - base) / ((size_t)MN * 4));
  Z = Z >= 4 ? 4 : 2;  // 4 blocks/CU if ws allows, else round-2 footprint

  roi_pool_kernel<<<R_ROIS, 256, 0, stream>>>(x, rois, ridx, A);

  // fc6: [512,25088] @ [25088,4096]
  gemm_splitk_kernel<<<256 * Z, 256, 0, stream>>>(A, W1, part, R_ROIS, NH, KDIM,
                                                  KDIM / Z, 256 * Z);
  reduce_relu_kernel<<<MN / 4 / 256, 256, 0, stream>>>(part, b1, fc6, MN, NH, Z);

  // fc7: [512,4096] @ [4096,4096]
  gemm_splitk_kernel<<<256 * Z, 256, 0, stream>>>(fc6, W2, part, R_ROIS, NH, NH,
                                                  NH / Z, 256 * Z);
  reduce_relu_kernel<<<MN / 4 / 256, 256, 0, stream>>>(part, b2, fc7, MN, NH, Z);

  head_kernel<<<R_ROIS, 256, 0, stream>>>(fc7, Wc, bc, Wsv, bs, (float*)d_out);
}

// Round 4
// 614.521 us; speedup vs baseline: 3.7486x; 1.1655x over previous
//
#include <hip/hip_runtime.h>
#include <math.h>

typedef __attribute__((ext_vector_type(8))) short short8;
typedef __attribute__((ext_vector_type(4))) short s16x4;
typedef __attribute__((ext_vector_type(4))) float f32x4;
typedef __attribute__((ext_vector_type(4))) unsigned u32x4;

#define R_ROIS 512
#define CCH 512
#define HH 50
#define WW 50
#define PPOOL 7
#define KDIM (CCH * PPOOL * PPOOL) /* 25088 */
#define NH 4096

__device__ __forceinline__ short f2bf(float f) {
  unsigned u = __builtin_bit_cast(unsigned, f);
  u += 0x7FFFu + ((u >> 16) & 1u);
  return (short)(u >> 16);
}
__device__ __forceinline__ float bf2f(short s) {
  unsigned u = ((unsigned)(unsigned short)s) << 16;
  return __builtin_bit_cast(float, u);
}
// HW packed fp32->bf16 (RNE): 1 VALU per 2 elements
__device__ __forceinline__ unsigned cvtpk(float lo, float hi) {
  unsigned r;
  asm("v_cvt_pk_bf16_f32 %0, %1, %2" : "=v"(r) : "v"(lo), "v"(hi));
  return r;
}

// ---------------- RoI max pool -> bf16 activation matrix A[512][25088] ---------
__global__ __launch_bounds__(256) void roi_pool_kernel(
    const float* __restrict__ x, const float* __restrict__ rois,
    const int* __restrict__ ridx, short* __restrict__ A) {
  __shared__ int hs[PPOOL], he[PPOOL], wss[PPOOL], wee[PPOOL];
  __shared__ int sidx;
  const int r = blockIdx.x;
  if (threadIdx.x == 0) {
    // raw rois columns: (ymin, xmin, ymax, xmax); reference permutes to (x,y,x,y)
    float ymin = rois[r * 4 + 0], xmin = rois[r * 4 + 1];
    float ymax = rois[r * 4 + 2], xmax = rois[r * 4 + 3];
    float sw = rintf(xmin * 0.0625f);
    float sh = rintf(ymin * 0.0625f);
    float ew = rintf(xmax * 0.0625f);
    float eh = rintf(ymax * 0.0625f);
    float bw = fmaxf(ew - sw + 1.0f, 1.0f) * (1.0f / 7.0f);
    float bh = fmaxf(eh - sh + 1.0f, 1.0f) * (1.0f / 7.0f);
    for (int p = 0; p < PPOOL; ++p) {
      wss[p] = (int)fminf(fmaxf(floorf(p * bw) + sw, 0.0f), 50.0f);
      wee[p] = (int)fminf(fmaxf(ceilf((p + 1) * bw) + sw, 0.0f), 50.0f);
      hs[p]  = (int)fminf(fmaxf(floorf(p * bh) + sh, 0.0f), 50.0f);
      he[p]  = (int)fminf(fmaxf(ceilf((p + 1) * bh) + sh, 0.0f), 50.0f);
    }
    sidx = ridx[r];
  }
  __syncthreads();
  const float* xb = x + (size_t)sidx * CCH * HH * WW;
  for (int o = threadIdx.x; o < KDIM; o += 256) {
    int c = o / 49;
    int pq = o - c * 49;
    int ph = pq / 7, pw = pq - ph * 7;
    const float* xc = xb + (size_t)c * (HH * WW);
    int h0 = hs[ph], h1 = he[ph], w0 = wss[pw], w1 = wee[pw];
    float mv = -INFINITY;
    for (int h = h0; h < h1; ++h) {
      const float* xr = xc + h * WW;
      for (int w = w0; w < w1; ++w) mv = fmaxf(mv, xr[w]);
    }
    A[(size_t)r * KDIM + o] = f2bf((h1 > h0 && w1 > w0) ? mv : 0.0f);
  }
}

// ---------------- bf16 MFMA split-K GEMM, BM=BN=128, XOR-swizzled LDS ---------
// Tiles stored [row][32k = 64B], swz byte ^= ((row&7)<<4): fragment b128 reads
// and staging b128 writes are conflict-free (2-way max). Per-k LDS traffic
// 1.5KB -> 21.3 FLOP/LDS-byte: LDS ceiling ~61us == W1 HBM floor (~65us).
// z-major XCD chunking: co-resident blocks stream the same k-slices.
__global__ __launch_bounds__(256, 2) void gemm_splitk_kernel(
    const short* __restrict__ A, const float* __restrict__ B,
    float* __restrict__ part, int M, int N, int K, int Ks, int nblk) {
  __shared__ __align__(16) char As[2][128 * 64];
  __shared__ __align__(16) char Bs[2][128 * 64];
  const int bid = blockIdx.x;
  const int vid = (bid & 7) * (nblk >> 3) + (bid >> 3);
  const int mb = vid & 3;
  const int nb = (vid >> 2) & 31;
  const int zb = vid >> 7;
  const int m0 = mb * 128, n0 = nb * 128;
  const int kbeg = zb * Ks, kend = kbeg + Ks;
  const int t = threadIdx.x;
  const int lane = t & 63, wid = t >> 6;
  const int wm = wid >> 1, wn = wid & 1;
  const int lr = lane & 15, kc = lane >> 4;
  const int ar = t >> 2, asg = t & 3;   // A staging: rows ar, ar+64, 16B seg asg
  const int bn = t & 127, bkh = t >> 7; // B staging: row n=bn, k-half bkh*16

  const short* aptr0 = A + (size_t)(m0 + ar) * K + asg * 8;
  const short* aptr1 = A + (size_t)(m0 + ar + 64) * K + asg * 8;
  const float* bbase = B + n0 + bn;

  // swizzled staging byte offsets (constant per thread)
  const int awz0 = (ar * 64 + asg * 16) ^ ((ar & 7) << 4);
  const int awz1 = ((ar + 64) * 64 + asg * 16) ^ ((ar & 7) << 4); // (ar+64)&7==ar&7
  const int bwz0 = (bn * 64 + bkh * 32) ^ ((bn & 7) << 4);
  const int bwz1 = bwz0 ^ 16;
  // swizzled fragment read bases (add m*1024 / nn*1024)
  const int aoff = (wm * 4096 + lr * 64 + kc * 16) ^ ((lr & 7) << 4);
  const int boff = (wn * 4096 + lr * 64 + kc * 16) ^ ((lr & 7) << 4);

  f32x4 acc[4][4] = {};
  short8 a_r0, a_r1;
  float br[16];

  // prologue: stage tile kbeg into buffer 0
  a_r0 = *(const short8*)(aptr0 + kbeg);
  a_r1 = *(const short8*)(aptr1 + kbeg);
  {
    const float* bp = bbase + (size_t)(kbeg + bkh * 16) * N;
    #pragma unroll
    for (int j = 0; j < 16; ++j) br[j] = bp[(size_t)j * N];
  }
  *(short8*)(As[0] + awz0) = a_r0;
  *(short8*)(As[0] + awz1) = a_r1;
  {
    u32x4 w0, w1;
    w0[0] = cvtpk(br[0], br[1]);   w0[1] = cvtpk(br[2], br[3]);
    w0[2] = cvtpk(br[4], br[5]);   w0[3] = cvtpk(br[6], br[7]);
    w1[0] = cvtpk(br[8], br[9]);   w1[1] = cvtpk(br[10], br[11]);
    w1[2] = cvtpk(br[12], br[13]); w1[3] = cvtpk(br[14], br[15]);
    *(u32x4*)(Bs[0] + bwz0) = w0;
    *(u32x4*)(Bs[0] + bwz1) = w1;
  }
  __syncthreads();

  int cur = 0;
  for (int k0 = kbeg + 32; k0 <= kend; k0 += 32) {
    bool more = (k0 < kend);
    if (more) {  // 1) issue next-tile global loads into regs
      a_r0 = *(const short8*)(aptr0 + k0);
      a_r1 = *(const short8*)(aptr1 + k0);
      const float* bp = bbase + (size_t)(k0 + bkh * 16) * N;
      #pragma unroll
      for (int j = 0; j < 16; ++j) br[j] = bp[(size_t)j * N];
    }
    // 2) compute on current buffer
    {
      short8 a[4], b[4];
      #pragma unroll
      for (int m = 0; m < 4; ++m)
        a[m] = *(const short8*)(As[cur] + aoff + m * 1024);
      #pragma unroll
      for (int n = 0; n < 4; ++n)
        b[n] = *(const short8*)(Bs[cur] + boff + n * 1024);
      #pragma unroll
      for (int m = 0; m < 4; ++m)
        #pragma unroll
        for (int n = 0; n < 4; ++n)
          acc[m][n] = __builtin_amdgcn_mfma_f32_16x16x32_bf16(a[m], b[n], acc[m][n], 0, 0, 0);
    }
    if (more) {  // 3) convert + write other buffer, one barrier
      *(short8*)(As[cur ^ 1] + awz0) = a_r0;
      *(short8*)(As[cur ^ 1] + awz1) = a_r1;
      u32x4 w0, w1;
      w0[0] = cvtpk(br[0], br[1]);   w0[1] = cvtpk(br[2], br[3]);
      w0[2] = cvtpk(br[4], br[5]);   w0[3] = cvtpk(br[6], br[7]);
      w1[0] = cvtpk(br[8], br[9]);   w1[1] = cvtpk(br[10], br[11]);
      w1[2] = cvtpk(br[12], br[13]); w1[3] = cvtpk(br[14], br[15]);
      *(u32x4*)(Bs[cur ^ 1] + bwz0) = w0;
      *(u32x4*)(Bs[cur ^ 1] + bwz1) = w1;
      __syncthreads();
      cur ^= 1;
    }
  }

  // ---- write fp32 partial; C/D map: col=lane&15, row=kc*4+j ----
  float* pz = part + (size_t)zb * M * N;
  #pragma unroll
  for (int m = 0; m < 4; ++m) {
    #pragma unroll
    for (int n = 0; n < 4; ++n) {
      int col = n0 + wn * 64 + n * 16 + lr;
      #pragma unroll
      for (int j = 0; j < 4; ++j) {
        int row = m0 + wm * 64 + m * 16 + kc * 4 + j;
        pz[(size_t)row * N + col] = acc[m][n][j];
      }
    }
  }
}

// ---------------- reduce split-K partials + bias + relu -> bf16 ---------------
__global__ __launch_bounds__(256) void reduce_relu_kernel(
    const float* __restrict__ part, const float* __restrict__ bias,
    short* __restrict__ out, int MN, int N, int Z) {
  int i = (blockIdx.x * 256 + threadIdx.x) * 4;
  if (i >= MN) return;
  const float4 b = *(const float4*)(bias + (i & (N - 1)));
  float4 s = *(const float4*)(part + i);
  for (int z = 1; z < Z; ++z) {
    float4 p = *(const float4*)(part + (size_t)z * MN + i);
    s.x += p.x; s.y += p.y; s.z += p.z; s.w += p.w;
  }
  s16x4 o;
  o.x = f2bf(fmaxf(s.x + b.x, 0.0f));
  o.y = f2bf(fmaxf(s.y + b.y, 0.0f));
  o.z = f2bf(fmaxf(s.z + b.z, 0.0f));
  o.w = f2bf(fmaxf(s.w + b.w, 0.0f));
  *(s16x4*)(out + i) = o;
}

// ---------------- small heads: 2 rois/block share the weight stream ----------
__global__ __launch_bounds__(256) void head_kernel(
    const short* __restrict__ fc7, const float* __restrict__ Wc,
    const float* __restrict__ bc, const float* __restrict__ Wsv,
    const float* __restrict__ bs, float* __restrict__ out) {
  __shared__ float r0v[NH], r1v[NH];
  __shared__ float partial[2][112];
  const int rb = blockIdx.x * 2, t = threadIdx.x;
  for (int k8 = t; k8 < NH / 8; k8 += 256) {
    short8 v0 = *(const short8*)(fc7 + (size_t)rb * NH + k8 * 8);
    short8 v1 = *(const short8*)(fc7 + (size_t)(rb + 1) * NH + k8 * 8);
    #pragma unroll
    for (int j = 0; j < 8; ++j) {
      r0v[k8 * 8 + j] = bf2f(v0[j]);
      r1v[k8 * 8 + j] = bf2f(v1[j]);
    }
  }
  __syncthreads();
  const int g = t >> 7, c = t & 127;  // two k-halves of 2048
  float a0 = 0.0f, a1 = 0.0f;
  if (c < 84) {
    const float* wp = Wc + c + (size_t)g * 2048 * 84;
    #pragma unroll 8
    for (int k = 0; k < 2048; ++k) {
      float w = wp[(size_t)k * 84];
      a0 += r0v[g * 2048 + k] * w;
      a1 += r1v[g * 2048 + k] * w;
    }
  } else if (c < 105) {
    const float* wp = Wsv + (c - 84) + (size_t)g * 2048 * 21;
    #pragma unroll 8
    for (int k = 0; k < 2048; ++k) {
      float w = wp[(size_t)k * 21];
      a0 += r0v[g * 2048 + k] * w;
      a1 += r1v[g * 2048 + k] * w;
    }
  }
  if (g == 0 && c < 105) { partial[0][c] = a0; partial[1][c] = a1; }
  __syncthreads();
  if (g == 1 && c < 105) {
    float v0 = partial[0][c] + a0;
    float v1 = partial[1][c] + a1;
    if (c < 84) {
      out[(size_t)rb * 84 + c] = v0 + bc[c];
      out[(size_t)(rb + 1) * 84 + c] = v1 + bc[c];
    } else {
      out[(size_t)R_ROIS * 84 + (size_t)rb * 21 + (c - 84)] = v0 + bs[c - 84];
      out[(size_t)R_ROIS * 84 + (size_t)(rb + 1) * 21 + (c - 84)] = v1 + bs[c - 84];
    }
  }
}

extern "C" void kernel_launch(void* const* d_in, const int* in_sizes, int n_in,
                              void* d_out, int out_size, void* d_ws, size_t ws_size,
                              hipStream_t stream) {
  const float* x    = (const float*)d_in[0];
  const float* rois = (const float*)d_in[1];
  const int*   ridx = (const int*)d_in[2];
  const float* W1   = (const float*)d_in[3];
  const float* b1   = (const float*)d_in[4];
  const float* W2   = (const float*)d_in[5];
  const float* b2   = (const float*)d_in[6];
  const float* Wc   = (const float*)d_in[7];
  const float* bc   = (const float*)d_in[8];
  const float* Wsv  = (const float*)d_in[9];
  const float* bs   = (const float*)d_in[10];

  short* A    = (short*)d_ws;                   // [512][25088] bf16 (~25.7 MB)
  short* fc6  = A + (size_t)R_ROIS * KDIM;      // [512][4096]  bf16 (4 MB)
  short* fc7  = fc6 + (size_t)R_ROIS * NH;      // [512][4096]  bf16 (4 MB)
  float* part = (float*)(fc7 + (size_t)R_ROIS * NH);  // Z x [512][4096] f32

  const int MN = R_ROIS * NH;
  const size_t base = ((size_t)R_ROIS * KDIM + 2 * (size_t)MN) * 2;
  int Z = (int)((ws_size - base) / ((size_t)MN * 4));
  Z = Z >= 4 ? 4 : 2;  // grid 512 (2 blocks/CU) if ws allows, else 256

  roi_pool_kernel<<<R_ROIS, 256, 0, stream>>>(x, rois, ridx, A);

  // fc6: [512,25088] @ [25088,4096]
  gemm_splitk_kernel<<<128 * Z, 256, 0, stream>>>(A, W1, part, R_ROIS, NH, KDIM,
                                                  KDIM / Z, 128 * Z);
  reduce_relu_kernel<<<MN / 4 / 256, 256, 0, stream>>>(part, b1, fc6, MN, NH, Z);

  // fc7: [512,4096] @ [4096,4096]
  gemm_splitk_kernel<<<128 * Z, 256, 0, stream>>>(fc6, W2, part, R_ROIS, NH, NH,
                                                  NH / Z, 128 * Z);
  reduce_relu_kernel<<<MN / 4 / 256, 256, 0, stream>>>(part, b2, fc7, MN, NH, Z);

  head_kernel<<<R_ROIS / 2, 256, 0, stream>>>(fc7, Wc, bc, Wsv, bs, (float*)d_out);
}